// Round 4
// baseline (715.951 us; speedup 1.0000x reference)
//
#include <hip/hip_runtime.h>

typedef __bf16 bf16x8 __attribute__((ext_vector_type(8)));
typedef __bf16 bf16x4 __attribute__((ext_vector_type(4)));
typedef float  f32x4  __attribute__((ext_vector_type(4)));

#define DDEC  176
#define DSP   54
#define K1    222
#define K1P   224
#define HID   256
#define HSTR  264            // h row stride (bf16 elems): 528B, 16B-aligned, 2-way bank alias
#define RPW   16             // rows per wave
#define WPB   2              // waves per block
#define BM    (RPW * WPB)    // 32 rows per block

#define WT1_OFF 57344        // 256*224
#define WT2_OFF 122880       // + 256*256
#define MLP_WS  131072       // + 32*256  (bf16 elems per MLP)

struct Biases {
  const float* b1[3];
  const float* b2[3];
};

// ---- convert/transpose weights to bf16: Wt0[256][224] (b0 folded at k=222),
// Wt1[256][256], Wt2[32][256] per MLP
__global__ __launch_bounds__(256) void prep_weights(
    const float* __restrict__ w0a, const float* __restrict__ w1a, const float* __restrict__ w2a,
    const float* __restrict__ w0b, const float* __restrict__ w1b, const float* __restrict__ w2b,
    const float* __restrict__ w0c, const float* __restrict__ w1c, const float* __restrict__ w2c,
    const float* __restrict__ b0a, const float* __restrict__ b0b, const float* __restrict__ b0c,
    __bf16* __restrict__ ws)
{
  int idx = blockIdx.x * 256 + threadIdx.x;
  if (idx >= 3 * MLP_WS) return;
  int m = idx / MLP_WS;
  int r = idx - m * MLP_WS;
  const float* w0 = (m == 0) ? w0a : (m == 1) ? w0b : w0c;
  const float* w1 = (m == 0) ? w1a : (m == 1) ? w1b : w1c;
  const float* w2 = (m == 0) ? w2a : (m == 1) ? w2b : w2c;
  const float* b0 = (m == 0) ? b0a : (m == 1) ? b0b : b0c;
  float v;
  if (r < WT1_OFF) {                 // Wt0[n][k] = w0[k][n]; k=222 -> b0[n]; k=223 -> 0
    int n = r / K1P;
    int k = r - n * K1P;
    v = (k < K1) ? w0[k * HID + n] : (k == K1 ? b0[n] : 0.0f);
  } else if (r < WT2_OFF) {          // Wt1[n][k] = w1[k][n]
    int rr = r - WT1_OFF;
    int n = rr >> 8, k = rr & 255;
    v = w1[k * HID + n];
  } else {                           // Wt2[n][k] = w2[k][n], n padded to 32
    int rr = r - WT2_OFF;
    int n = rr >> 8, k = rr & 255;
    int od = (m == 0) ? 8 : 24;
    v = (n < od) ? w2[k * od + n] : 0.0f;
  }
  ws[idx] = (__bf16)v;
}

__device__ __forceinline__ bf16x8 pack8(float2 a, float2 b, float2 c, float2 d) {
  return (bf16x8){(__bf16)a.x, (__bf16)a.y, (__bf16)b.x, (__bf16)b.y,
                  (__bf16)c.x, (__bf16)c.y, (__bf16)d.x, (__bf16)d.y};
}

// Wave-independent fused trunk: each wave owns 16 rows x 256 cols, zero barriers.
// Hidden dim processed in two halves of 128 (acc[8] live) to bound VGPR pressure;
// h1/h2 staged once into registers (hb[8]) so epilogue overwrites can't race reads.
__global__ __launch_bounds__(128, 2) void trunk_fused(
    const float* __restrict__ sparse, const float* __restrict__ dec,
    const __bf16* __restrict__ ws, float* __restrict__ out,
    Biases bp)
{
  __shared__ __align__(16) __bf16 hls[BM * HSTR];

  const int tid  = threadIdx.x;
  const int lane = tid & 63;
  const int wid  = tid >> 6;
  const int lr   = lane & 15;        // 16-dim index (frag row/col)
  const int lg   = lane >> 4;        // k/reg sub-group
  const long grow = (long)blockIdx.x * BM + wid * RPW + lr;
  __bf16* hrow = &hls[(wid * RPW + lr) * HSTR];

  // ---- gather x into registers: xreg[kp] = x[row][(kp*4+lg)*8 .. +8)
  // (exactly the MFMA B-fragment layout -> layer 0 needs no LDS at all)
  bf16x8 xreg[7];
  {
    const float* drow = dec + grow * DDEC;
    const float* srow = sparse + grow * DSP;
    // dec float-offsets (joint*8) packed per kp, 16-bit fields indexed by lg
    const unsigned long long D0 = 0ull  | (24ull << 16) | (48ull << 32) | (72ull << 48);
    const unsigned long long D1 = 96ull | (104ull << 16) | (112ull << 32) | (120ull << 48);
    const unsigned long long D2 = 128ull| (136ull << 16) | (144ull << 32) | (152ull << 48);
    const unsigned long long D3 = 160ull| (168ull << 16) | (152ull << 32) | (136ull << 48);
    const unsigned long long D4 = 112ull| (72ull  << 16) | (48ull  << 32) | (24ull  << 48);
    const unsigned long long DOFF[5] = {D0, D1, D2, D3, D4};
    #pragma unroll
    for (int kp = 0; kp < 5; ++kp) {
      int off = (int)((DOFF[kp] >> (lg * 16)) & 0xffffull);
      const float4* p = (const float4*)(drow + off);
      float4 a = p[0], b = p[1];
      xreg[kp] = (bf16x8){(__bf16)a.x, (__bf16)a.y, (__bf16)a.z, (__bf16)a.w,
                          (__bf16)b.x, (__bf16)b.y, (__bf16)b.z, (__bf16)b.w};
    }
    {  // kp=5: lg==0 -> dec joint 0; lg>=1 -> sparse[ (lg-1)*8 .. +8 )
      const float* p = (lg == 0) ? drow : (srow + (lg - 1) * 8);
      const float2* q = (const float2*)p;
      xreg[5] = pack8(q[0], q[1], q[2], q[3]);
    }
    {  // kp=6: lg<3 -> sparse[24+lg*8 ..); lg==3 -> sparse[48..53], 1.0 (b0 hook), 0
      const float* p = srow + 24 + lg * 8;
      const float2* q = (const float2*)p;
      float2 t = (lg < 3) ? q[3] : make_float2(1.0f, 0.0f);
      xreg[6] = pack8(q[0], q[1], q[2], t);
    }
  }

  for (int m = 0; m < 3; ++m) {
    const __bf16* wt0 = ws + m * MLP_WS;
    const __bf16* wt1 = wt0 + WT1_OFF;
    const __bf16* wt2 = wt0 + WT2_OFF;
    const int odim = (m == 0) ? 8 : 24;

    // ---- layer 0: h1^T = W0^T x^T  (K=224, bias folded at k=222), 2 halves
    #pragma unroll
    for (int hf = 0; hf < 2; ++hf) {
      f32x4 acc[8];
      #pragma unroll
      for (int nb = 0; nb < 8; ++nb) acc[nb] = (f32x4){0.f, 0.f, 0.f, 0.f};
      const __bf16* wb = wt0 + (size_t)(hf * 128 + lr) * K1P + lg * 8;
      #pragma unroll
      for (int kp = 0; kp < 7; ++kp) {
        #pragma unroll
        for (int nb = 0; nb < 8; ++nb) {
          bf16x8 a = *(const bf16x8*)(wb + (size_t)nb * 16 * K1P + kp * 32);
          acc[nb] = __builtin_amdgcn_mfma_f32_16x16x32_bf16(a, xreg[kp], acc[nb], 0, 0, 0);
        }
      }
      #pragma unroll
      for (int nb = 0; nb < 8; ++nb) {
        bf16x4 h;
        #pragma unroll
        for (int i = 0; i < 4; ++i) {
          float v = acc[nb][i];
          v = (v > 0.f) ? v : 0.01f * v;
          h[i] = (__bf16)v;
        }
        *(bf16x4*)(hrow + hf * 128 + nb * 16 + lg * 4) = h;
      }
    }

    // stage h1 fragment into registers (shared by both layer-1 halves)
    bf16x8 hb[8];
    #pragma unroll
    for (int kk = 0; kk < 8; ++kk)
      hb[kk] = *(const bf16x8*)(hrow + kk * 32 + lg * 8);

    // ---- layer 1: h2^T = W1^T h1^T + b1  (K=256), 2 halves; h2 overwrites h1
    {
      const float* b1 = bp.b1[m];
      #pragma unroll
      for (int hf = 0; hf < 2; ++hf) {
        f32x4 acc[8];
        #pragma unroll
        for (int nb = 0; nb < 8; ++nb) acc[nb] = (f32x4){0.f, 0.f, 0.f, 0.f};
        const __bf16* wb = wt1 + (size_t)(hf * 128 + lr) * HID + lg * 8;
        #pragma unroll
        for (int kk = 0; kk < 8; ++kk) {
          #pragma unroll
          for (int nb = 0; nb < 8; ++nb) {
            bf16x8 a = *(const bf16x8*)(wb + (size_t)nb * 16 * HID + kk * 32);
            acc[nb] = __builtin_amdgcn_mfma_f32_16x16x32_bf16(a, hb[kk], acc[nb], 0, 0, 0);
          }
        }
        #pragma unroll
        for (int nb = 0; nb < 8; ++nb) {
          const int col0 = hf * 128 + nb * 16 + lg * 4;
          float4 bv = *(const float4*)(b1 + col0);
          bf16x4 h;
          h[0] = (__bf16)([](float v){ return v > 0.f ? v : 0.01f * v; }(acc[nb][0] + bv.x));
          h[1] = (__bf16)([](float v){ return v > 0.f ? v : 0.01f * v; }(acc[nb][1] + bv.y));
          h[2] = (__bf16)([](float v){ return v > 0.f ? v : 0.01f * v; }(acc[nb][2] + bv.z));
          h[3] = (__bf16)([](float v){ return v > 0.f ? v : 0.01f * v; }(acc[nb][3] + bv.w));
          *(bf16x4*)(hrow + col0) = h;
        }
      }
    }

    // stage h2 fragment (reuse hb regs)
    #pragma unroll
    for (int kk = 0; kk < 8; ++kk)
      hb[kk] = *(const bf16x8*)(hrow + kk * 32 + lg * 8);

    // ---- layer 2: res^T = W2^T h2^T + b2  (out padded to 32 cols)
    f32x4 a2[2] = {(f32x4){0.f,0.f,0.f,0.f}, (f32x4){0.f,0.f,0.f,0.f}};
    {
      const __bf16* wb2 = wt2 + (size_t)lr * HID + lg * 8;
      #pragma unroll
      for (int kk = 0; kk < 8; ++kk) {
        #pragma unroll
        for (int nb = 0; nb < 2; ++nb) {
          bf16x8 a = *(const bf16x8*)(wb2 + (size_t)nb * 16 * HID + kk * 32);
          a2[nb] = __builtin_amdgcn_mfma_f32_16x16x32_bf16(a, hb[kk], a2[nb], 0, 0, 0);
        }
      }
    }
    const float* b2 = bp.b2[m];
    if (m == 2) {
      #pragma unroll
      for (int nb = 0; nb < 2; ++nb) {
        const int col0 = nb * 16 + lg * 4;
        if (col0 < 24) {
          float4 bv = *(const float4*)(b2 + col0);
          float4 o;
          o.x = a2[nb][0] + bv.x;
          o.y = a2[nb][1] + bv.y;
          o.z = a2[nb][2] + bv.z;
          o.w = a2[nb][3] + bv.w;
          *(float4*)(out + grow * 24 + col0) = o;
        }
      }
    } else {
      // write res (bias applied, bf16) into wave-private strip, then update xreg
      #pragma unroll
      for (int nb = 0; nb < 2; ++nb) {
        const int col0 = nb * 16 + lg * 4;
        if (col0 < odim) {
          float4 bv = *(const float4*)(b2 + col0);
          bf16x4 r;
          r[0] = (__bf16)(a2[nb][0] + bv.x);
          r[1] = (__bf16)(a2[nb][1] + bv.y);
          r[2] = (__bf16)(a2[nb][2] + bv.z);
          r[3] = (__bf16)(a2[nb][3] + bv.w);
          *(bf16x4*)(hrow + col0) = r;
        }
      }
      if (m == 0) {
        // res1 (joint 9, 8 vals) -> x chunks 3 (kp0,lg3) and 17 (kp4,lg1)
        bf16x8 r = *(const bf16x8*)(hrow + 0);
        if (lg == 3) xreg[0] = r;
        if (lg == 1) xreg[4] = r;
      } else {
        // res2: joint6 -> chunks 2 (kp0,lg2) & 18 (kp4,lg2);
        //       joint9 -> chunks 3 (kp0,lg3) & 17 (kp4,lg1); joint12 -> chunk 4 (kp1,lg0)
        const int off = (lg == 0) ? 16 : (lg == 2) ? 0 : 8;
        bf16x8 r = *(const bf16x8*)(hrow + off);
        if (lg == 0)      { xreg[1] = r; }
        else if (lg == 1) { xreg[4] = r; }
        else if (lg == 2) { xreg[0] = r; xreg[4] = r; }
        else              { xreg[0] = r; }
      }
    }
  }
}

extern "C" void kernel_launch(void* const* d_in, const int* in_sizes, int n_in,
                              void* d_out, int out_size, void* d_ws, size_t ws_size,
                              hipStream_t stream)
{
  const float* sparse = (const float*)d_in[0];
  const float* dec    = (const float*)d_in[1];
  Biases bp;
  const float* w0[3]; const float* w1[3]; const float* w2[3]; const float* b0[3];
  for (int m = 0; m < 3; ++m) {
    w0[m]    = (const float*)d_in[2 + m * 6 + 0];
    b0[m]    = (const float*)d_in[2 + m * 6 + 1];
    w1[m]    = (const float*)d_in[2 + m * 6 + 2];
    bp.b1[m] = (const float*)d_in[2 + m * 6 + 3];
    w2[m]    = (const float*)d_in[2 + m * 6 + 4];
    bp.b2[m] = (const float*)d_in[2 + m * 6 + 5];
  }
  __bf16* ws = (__bf16*)d_ws;
  const int nrows = in_sizes[0] / DSP;   // 131072 (divisible by BM=32)

  const int prep_total = 3 * MLP_WS;
  prep_weights<<<(prep_total + 255) / 256, 256, 0, stream>>>(
      w0[0], w1[0], w2[0], w0[1], w1[1], w2[1], w0[2], w1[2], w2[2],
      b0[0], b0[1], b0[2], ws);

  const int nblocks = nrows / BM;
  trunk_fused<<<nblocks, 128, 0, stream>>>(sparse, dec, ws, (float*)d_out, bp);
}

// Round 5
// 203.069 us; speedup vs baseline: 3.5257x; 3.5257x over previous
//
#include <hip/hip_runtime.h>

typedef __bf16 bf16x8 __attribute__((ext_vector_type(8)));
typedef __bf16 bf16x4 __attribute__((ext_vector_type(4)));
typedef float  f32x4  __attribute__((ext_vector_type(4)));

#define DDEC  176
#define DSP   54
#define HID   256
#define RPW   16             // rows per wave
#define BM    128            // rows per block (8 waves)
// ws layout per MLP (bf16 elems): W0p[256][256] (k>=222 zero, k==222 = b0),
// W1p[256][256], W2p[32][256]
#define W1_OFF   65536
#define W2_OFF   131072
#define MLP_WS   139264

#define LDS_ELEMS (32768 * 2 + 8192)   // bufA + bufB + 8 x 1KB-elem strips = 144KB
static_assert(LDS_ELEMS * 2 <= 160 * 1024, "LDS over budget");

struct Biases { const float* b1[3]; const float* b2[3]; };

// ---- prep: pad/transpose weights to bf16 [col][256 k] per layer
__global__ __launch_bounds__(256) void prep_weights(
    const float* __restrict__ w0a, const float* __restrict__ w1a, const float* __restrict__ w2a,
    const float* __restrict__ w0b, const float* __restrict__ w1b, const float* __restrict__ w2b,
    const float* __restrict__ w0c, const float* __restrict__ w1c, const float* __restrict__ w2c,
    const float* __restrict__ b0a, const float* __restrict__ b0b, const float* __restrict__ b0c,
    __bf16* __restrict__ ws)
{
  int idx = blockIdx.x * 256 + threadIdx.x;
  if (idx >= 3 * MLP_WS) return;
  int m = idx / MLP_WS;
  int r = idx - m * MLP_WS;
  const float* w0 = (m == 0) ? w0a : (m == 1) ? w0b : w0c;
  const float* w1 = (m == 0) ? w1a : (m == 1) ? w1b : w1c;
  const float* w2 = (m == 0) ? w2a : (m == 1) ? w2b : w2c;
  const float* b0 = (m == 0) ? b0a : (m == 1) ? b0b : b0c;
  float v;
  if (r < W1_OFF) {
    int n = r >> 8, k = r & 255;
    v = (k < 222) ? w0[k * HID + n] : (k == 222 ? b0[n] : 0.0f);
  } else if (r < W2_OFF) {
    int rr = r - W1_OFF;
    int n = rr >> 8, k = rr & 255;
    v = w1[k * HID + n];
  } else {
    int rr = r - W2_OFF;
    int n = rr >> 8, k = rr & 255;
    int od = (m == 0) ? 8 : 24;
    v = (n < od) ? w2[k * od + n] : 0.0f;
  }
  ws[idx] = (__bf16)v;
}

__device__ __forceinline__ float lrelu(float v) { return v > 0.f ? v : 0.01f * v; }

__device__ __forceinline__ void gload16(const void* g, void* l) {
  __builtin_amdgcn_global_load_lds(
      (const __attribute__((address_space(1))) void*)g,
      (__attribute__((address_space(3))) void*)l, 16, 0, 0);
}

// stage NITER*8KB of padded weights [cols][256k] into buf; source pre-swizzled so
// that LDS content at byte a holds W[col=a>>9][k=((a&511)^((col&7)<<4))>>1]
template<int NITER>
__device__ __forceinline__ void stage(const __bf16* __restrict__ wsrc, __bf16* buf, int tid) {
  const int wid = tid >> 6, lane = tid & 63;
  #pragma unroll
  for (int i = 0; i < NITER; ++i) {
    int a = i * 8192 + wid * 1024 + lane * 16;
    int lc = a >> 9;
    int un = (a & 511) ^ ((lc & 7) << 4);
    gload16(wsrc + lc * 256 + (un >> 1), (char*)buf + i * 8192 + wid * 1024);
  }
}

// one column-half: acc[nb] += Wt[16nb+lr][k] x B[k], swizzled ds_read_b128 A-frags
template<int NK>
__device__ __forceinline__ void gemm_half(const __bf16* __restrict__ buf,
                                          const bf16x8* __restrict__ bfr,
                                          f32x4* __restrict__ acc, int lr, int lg) {
  const int sw = (lr & 7) << 4;
  #pragma unroll
  for (int kk = 0; kk < NK; ++kk) {
    const int inner = ((kk << 6) + (lg << 4)) ^ sw;
    bf16x8 a[8];
    #pragma unroll
    for (int nb = 0; nb < 8; ++nb)
      a[nb] = *(const bf16x8*)((const char*)buf + (((16 * nb + lr) << 9) + inner));
    #pragma unroll
    for (int nb = 0; nb < 8; ++nb)
      acc[nb] = __builtin_amdgcn_mfma_f32_16x16x32_bf16(a[nb], bfr[kk], acc[nb], 0, 0, 0);
  }
}

// acc (h^T fragments, 256 cols) -> hb[8] B-fragments via wave-private swizzled strip
template<bool BIAS>
__device__ __forceinline__ void transition(const f32x4* __restrict__ acc,
                                           bf16x8* __restrict__ hb, __bf16* strip,
                                           const float* __restrict__ bias, int lr, int lg) {
  const int sw = (lr & 7) << 4;
  char* sb = (char*)strip;
  #pragma unroll
  for (int g = 0; g < 4; ++g) {
    #pragma unroll
    for (int nbl = 0; nbl < 4; ++nbl) {
      const int nb = 4 * g + nbl;
      float bx = 0.f, by = 0.f, bz = 0.f, bw = 0.f;
      if (BIAS) {
        float4 bv = *(const float4*)(bias + nb * 16 + lg * 4);
        bx = bv.x; by = bv.y; bz = bv.z; bw = bv.w;
      }
      bf16x4 h;
      h[0] = (__bf16)lrelu(acc[nb][0] + bx);
      h[1] = (__bf16)lrelu(acc[nb][1] + by);
      h[2] = (__bf16)lrelu(acc[nb][2] + bz);
      h[3] = (__bf16)lrelu(acc[nb][3] + bw);
      *(bf16x4*)(sb + ((lr * 128 + nbl * 32 + lg * 8) ^ sw)) = h;
    }
    hb[2 * g]     = *(const bf16x8*)(sb + ((lr * 128 + lg * 16) ^ sw));
    hb[2 * g + 1] = *(const bf16x8*)(sb + ((lr * 128 + 64 + lg * 16) ^ sw));
  }
}

__device__ __forceinline__ bf16x8 pack8(float2 a, float2 b, float2 c, float2 d) {
  return (bf16x8){(__bf16)a.x, (__bf16)a.y, (__bf16)b.x, (__bf16)b.y,
                  (__bf16)c.x, (__bf16)c.y, (__bf16)d.x, (__bf16)d.y};
}

__global__ __launch_bounds__(512, 2) void trunk_fused(
    const float* __restrict__ sparse, const float* __restrict__ dec,
    const __bf16* __restrict__ ws, float* __restrict__ out, Biases bp)
{
  __shared__ __align__(16) __bf16 lds[LDS_ELEMS];
  __bf16* bufA = lds;
  __bf16* bufB = lds + 32768;

  const int tid  = threadIdx.x;
  const int lane = tid & 63;
  const int wid  = tid >> 6;
  const int lr   = lane & 15;
  const int lg   = lane >> 4;
  __bf16* strip = lds + 65536 + wid * 1024;
  const long grow = (long)blockIdx.x * BM + wid * RPW + lr;

  // ---- gather x into registers: xreg[kp] = x[row][(kp*4+lg)*8 .. +8)
  bf16x8 xreg[7];
  {
    const float* drow = dec + grow * DDEC;
    const float* srow = sparse + grow * DSP;
    const unsigned long long D0 = 0ull  | (24ull << 16) | (48ull << 32) | (72ull << 48);
    const unsigned long long D1 = 96ull | (104ull << 16) | (112ull << 32) | (120ull << 48);
    const unsigned long long D2 = 128ull| (136ull << 16) | (144ull << 32) | (152ull << 48);
    const unsigned long long D3 = 160ull| (168ull << 16) | (152ull << 32) | (136ull << 48);
    const unsigned long long D4 = 112ull| (72ull  << 16) | (48ull  << 32) | (24ull  << 48);
    const unsigned long long DOFF[5] = {D0, D1, D2, D3, D4};
    #pragma unroll
    for (int kp = 0; kp < 5; ++kp) {
      int off = (int)((DOFF[kp] >> (lg * 16)) & 0xffffull);
      const float4* p = (const float4*)(drow + off);
      float4 a = p[0], b = p[1];
      xreg[kp] = (bf16x8){(__bf16)a.x, (__bf16)a.y, (__bf16)a.z, (__bf16)a.w,
                          (__bf16)b.x, (__bf16)b.y, (__bf16)b.z, (__bf16)b.w};
    }
    {
      const float* p = (lg == 0) ? drow : (srow + (lg - 1) * 8);
      const float2* q = (const float2*)p;
      xreg[5] = pack8(q[0], q[1], q[2], q[3]);
    }
    {
      const float* p = srow + 24 + lg * 8;
      const float2* q = (const float2*)p;
      float2 t = (lg < 3) ? q[3] : make_float2(1.0f, 0.0f);
      xreg[6] = pack8(q[0], q[1], q[2], t);
    }
  }

  for (int m = 0; m < 3; ++m) {
    const __bf16* W0 = ws + m * MLP_WS;
    const __bf16* W1 = W0 + W1_OFF;
    const __bf16* W2 = W0 + W2_OFF;

    f32x4 acc[16];
    bf16x8 hb[8];

    #pragma unroll
    for (int nb = 0; nb < 16; ++nb) acc[nb] = (f32x4){0.f, 0.f, 0.f, 0.f};

    // S0: stage W0 cols 0-127
    stage<8>(W0, bufA, tid);
    __syncthreads();
    // S1: stage W0 cols 128-255 | compute L0 half A
    stage<8>(W0 + 128 * 256, bufB, tid);
    gemm_half<7>(bufA, xreg, &acc[0], lr, lg);
    __syncthreads();
    // S2: stage W1 cols 0-127 | compute L0 half B
    stage<8>(W1, bufA, tid);
    gemm_half<7>(bufB, xreg, &acc[8], lr, lg);
    __syncthreads();
    // T0: h1 -> hb (bias folded into K, lrelu only)
    transition<false>(acc, hb, strip, nullptr, lr, lg);
    #pragma unroll
    for (int nb = 0; nb < 16; ++nb) acc[nb] = (f32x4){0.f, 0.f, 0.f, 0.f};
    // S3: stage W1 cols 128-255 | compute L1 half A
    stage<8>(W1 + 128 * 256, bufB, tid);
    gemm_half<8>(bufA, hb, &acc[0], lr, lg);
    __syncthreads();
    // S4: stage W2 (16KB) | compute L1 half B
    stage<2>(W2, bufA, tid);
    gemm_half<8>(bufB, hb, &acc[8], lr, lg);
    __syncthreads();
    // T1: h2 -> hb (bias b1 + lrelu)
    transition<true>(acc, hb, strip, bp.b1[m], lr, lg);

    // S5: layer 2 (32 padded cols from bufA)
    f32x4 a2[2] = {(f32x4){0.f,0.f,0.f,0.f}, (f32x4){0.f,0.f,0.f,0.f}};
    {
      const int sw = (lr & 7) << 4;
      #pragma unroll
      for (int kk = 0; kk < 8; ++kk) {
        const int inner = ((kk << 6) + (lg << 4)) ^ sw;
        #pragma unroll
        for (int nb = 0; nb < 2; ++nb) {
          bf16x8 a = *(const bf16x8*)((const char*)bufA + (((16 * nb + lr) << 9) + inner));
          a2[nb] = __builtin_amdgcn_mfma_f32_16x16x32_bf16(a, hb[kk], a2[nb], 0, 0, 0);
        }
      }
    }
    const float* b2 = bp.b2[m];
    if (m == 2) {
      #pragma unroll
      for (int nb = 0; nb < 2; ++nb) {
        const int col0 = nb * 16 + lg * 4;
        if (col0 < 24) {
          float4 bv = *(const float4*)(b2 + col0);
          float4 o;
          o.x = a2[nb][0] + bv.x;
          o.y = a2[nb][1] + bv.y;
          o.z = a2[nb][2] + bv.z;
          o.w = a2[nb][3] + bv.w;
          *(float4*)(out + grow * 24 + col0) = o;
        }
      }
    } else {
      const int odim = (m == 0) ? 8 : 24;
      const int sw = (lr & 7) << 4;
      char* sb = (char*)strip;
      #pragma unroll
      for (int nb = 0; nb < 2; ++nb) {
        const int col0 = nb * 16 + lg * 4;
        if (col0 < odim) {
          float4 bv = *(const float4*)(b2 + col0);
          bf16x4 r;
          r[0] = (__bf16)(a2[nb][0] + bv.x);
          r[1] = (__bf16)(a2[nb][1] + bv.y);
          r[2] = (__bf16)(a2[nb][2] + bv.z);
          r[3] = (__bf16)(a2[nb][3] + bv.w);
          *(bf16x4*)(sb + ((lr * 128 + col0 * 2) ^ sw)) = r;
        }
      }
      if (m == 0) {
        // res1 (joint 9, cols 0-7) -> x chunks 3 (kp0,lg3) and 17 (kp4,lg1)
        bf16x8 r = *(const bf16x8*)(sb + ((lr * 128) ^ sw));
        if (lg == 3) xreg[0] = r;
        if (lg == 1) xreg[4] = r;
      } else {
        // res2: joint6(cols0-7)->chunks 2/18; joint9(8-15)->3/17; joint12(16-23)->4
        const int offb = (lg == 0) ? 32 : (lg == 2) ? 0 : 16;
        bf16x8 r = *(const bf16x8*)(sb + ((lr * 128 + offb) ^ sw));
        if (lg == 0)      { xreg[1] = r; }
        else if (lg == 1) { xreg[4] = r; }
        else if (lg == 2) { xreg[0] = r; xreg[4] = r; }
        else              { xreg[0] = r; }
      }
    }
    __syncthreads();   // bufA/bufB reads done before next MLP restages
  }
}

extern "C" void kernel_launch(void* const* d_in, const int* in_sizes, int n_in,
                              void* d_out, int out_size, void* d_ws, size_t ws_size,
                              hipStream_t stream)
{
  const float* sparse = (const float*)d_in[0];
  const float* dec    = (const float*)d_in[1];
  Biases bp;
  const float* w0[3]; const float* w1[3]; const float* w2[3]; const float* b0[3];
  for (int m = 0; m < 3; ++m) {
    w0[m]    = (const float*)d_in[2 + m * 6 + 0];
    b0[m]    = (const float*)d_in[2 + m * 6 + 1];
    w1[m]    = (const float*)d_in[2 + m * 6 + 2];
    bp.b1[m] = (const float*)d_in[2 + m * 6 + 3];
    w2[m]    = (const float*)d_in[2 + m * 6 + 4];
    bp.b2[m] = (const float*)d_in[2 + m * 6 + 5];
  }
  __bf16* ws = (__bf16*)d_ws;
  const int nrows = in_sizes[0] / DSP;   // 131072 = 1024 * 128

  const int prep_total = 3 * MLP_WS;
  prep_weights<<<(prep_total + 255) / 256, 256, 0, stream>>>(
      w0[0], w1[0], w2[0], w0[1], w1[1], w2[1], w0[2], w1[2], w2[2],
      b0[0], b0[1], b0[2], ws);

  const int nblocks = nrows / BM;
  trunk_fused<<<nblocks, 512, 0, stream>>>(sparse, dec, ws, (float*)d_out, bp);
}

// Round 6
// 182.314 us; speedup vs baseline: 3.9270x; 1.1138x over previous
//
#include <hip/hip_runtime.h>

typedef __bf16 bf16x8 __attribute__((ext_vector_type(8)));
typedef __bf16 bf16x4 __attribute__((ext_vector_type(4)));
typedef float  f32x16 __attribute__((ext_vector_type(16)));

#define DDEC  176
#define DSP   54
#define HID   256
#define RPW   32             // rows per wave (32x32 MFMA N-dim)
#define WPB   4              // waves per block
#define BM    (RPW * WPB)    // 128 rows per block
#define QSZ   16384          // elems per 64-col weight quarter
#define W1_OFF 65536
#define W2_OFF 131072
#define MLP_WS 139264

struct Biases { const float* b1[3]; const float* b2[3]; };

// ---- prep: pad/transpose weights to bf16 [col][256 k] per layer
// W0p[256][256] (k<222 = w0[k][n], k==222 = b0[n], else 0), W1p[256][256], W2p[32][256]
__global__ __launch_bounds__(256) void prep_weights(
    const float* __restrict__ w0a, const float* __restrict__ w1a, const float* __restrict__ w2a,
    const float* __restrict__ w0b, const float* __restrict__ w1b, const float* __restrict__ w2b,
    const float* __restrict__ w0c, const float* __restrict__ w1c, const float* __restrict__ w2c,
    const float* __restrict__ b0a, const float* __restrict__ b0b, const float* __restrict__ b0c,
    __bf16* __restrict__ ws)
{
  int idx = blockIdx.x * 256 + threadIdx.x;
  if (idx >= 3 * MLP_WS) return;
  int m = idx / MLP_WS;
  int r = idx - m * MLP_WS;
  const float* w0 = (m == 0) ? w0a : (m == 1) ? w0b : w0c;
  const float* w1 = (m == 0) ? w1a : (m == 1) ? w1b : w1c;
  const float* w2 = (m == 0) ? w2a : (m == 1) ? w2b : w2c;
  const float* b0 = (m == 0) ? b0a : (m == 1) ? b0b : b0c;
  float v;
  if (r < W1_OFF) {
    int n = r >> 8, k = r & 255;
    v = (k < 222) ? w0[k * HID + n] : (k == 222 ? b0[n] : 0.0f);
  } else if (r < W2_OFF) {
    int rr = r - W1_OFF;
    int n = rr >> 8, k = rr & 255;
    v = w1[k * HID + n];
  } else {
    int rr = r - W2_OFF;
    int n = rr >> 8, k = rr & 255;
    int od = (m == 0) ? 8 : 24;
    v = (n < od) ? w2[k * od + n] : 0.0f;
  }
  ws[idx] = (__bf16)v;
}

__device__ __forceinline__ float lrelu(float v) { return v > 0.f ? v : 0.01f * v; }

__device__ __forceinline__ void gload16(const void* g, void* l) {
  __builtin_amdgcn_global_load_lds(
      (const __attribute__((address_space(1))) void*)g,
      (__attribute__((address_space(3))) void*)l, 16, 0, 0);
}

// stage ROUNDS*4KB of [col][256k] weights; source pre-swizzled so LDS byte a holds
// W[col = a>>9][k_byte = (a&511) ^ ((col&31)<<4)]
template<int ROUNDS>
__device__ __forceinline__ void stage(const __bf16* __restrict__ wsrc, __bf16* buf, int tid) {
  #pragma unroll
  for (int r = 0; r < ROUNDS; ++r) {
    const int a  = (r * 256 + tid) * 16;
    const int lc = a >> 9;
    const int un = (a & 511) ^ ((lc & 31) << 4);
    gload16(wsrc + lc * 256 + (un >> 1), (char*)buf + r * 4096 + (tid >> 6) * 1024);
  }
}

// 64-col quarter: acc{0,1} += W[32b+r32][k] x B[k]  (swizzled ds_read_b128 A-frags)
template<int NKK>
__device__ __forceinline__ void gemm2(const __bf16* buf, const bf16x8* bfr,
                                      f32x16& acc0, f32x16& acc1, int r32, int h) {
  const int sw = r32 << 4;
  #pragma unroll
  for (int kk = 0; kk < NKK; ++kk) {
    const int inner = ((kk << 5) + (h << 4)) ^ sw;
    bf16x8 a0 = *(const bf16x8*)((const char*)buf + (r32 << 9) + inner);
    bf16x8 a1 = *(const bf16x8*)((const char*)buf + ((32 + r32) << 9) + inner);
    acc0 = __builtin_amdgcn_mfma_f32_32x32x16_bf16(a0, bfr[kk], acc0, 0, 0, 0);
    acc1 = __builtin_amdgcn_mfma_f32_32x32x16_bf16(a1, bfr[kk], acc1, 0, 0, 0);
  }
}

template<int NKK>
__device__ __forceinline__ void gemm1(const __bf16* buf, const bf16x8* bfr,
                                      f32x16& acc0, int r32, int h) {
  const int sw = r32 << 4;
  #pragma unroll
  for (int kk = 0; kk < NKK; ++kk) {
    const int inner = ((kk << 5) + (h << 4)) ^ sw;
    bf16x8 a0 = *(const bf16x8*)((const char*)buf + (r32 << 9) + inner);
    acc0 = __builtin_amdgcn_mfma_f32_32x32x16_bf16(a0, bfr[kk], acc0, 0, 0, 0);
  }
}

__device__ __forceinline__ bf16x4 shfl32(bf16x4 x) {
  union { bf16x4 v; unsigned long long u; } t;
  t.v = x;
  t.u = __shfl_xor(t.u, 32, 64);
  return t.v;
}
__device__ __forceinline__ bf16x8 cat44(bf16x4 lo, bf16x4 hi) {
  return (bf16x8){lo[0], lo[1], lo[2], lo[3], hi[0], hi[1], hi[2], hi[3]};
}

struct Frag2 { bf16x8 f0, f1; };

// One 32-col D block -> 2 next-layer B-frags (k = 32nb..+16, 32nb+16..+32).
// D layout (verified): n = lane&31, m = (reg&3) + 8*(reg>>2) + 4*h. Lane-half h owns
// quads {2t+h}; one shfl_xor(32) per 2 quads completes each frag.
template<bool BIAS, bool LR>
__device__ __forceinline__ Frag2 d2frags(const f32x16 acc, const float* bias, int h) {
  bf16x4 pk[4];
  #pragma unroll
  for (int t = 0; t < 4; ++t) {
    float bx = 0.f, by = 0.f, bz = 0.f, bw = 0.f;
    if (BIAS) {
      float4 bv = *(const float4*)(bias + 8 * t + 4 * h);
      bx = bv.x; by = bv.y; bz = bv.z; bw = bv.w;
    }
    float v0 = acc[4 * t] + bx, v1 = acc[4 * t + 1] + by;
    float v2 = acc[4 * t + 2] + bz, v3 = acc[4 * t + 3] + bw;
    if (LR) { v0 = lrelu(v0); v1 = lrelu(v1); v2 = lrelu(v2); v3 = lrelu(v3); }
    pk[t] = (bf16x4){(__bf16)v0, (__bf16)v1, (__bf16)v2, (__bf16)v3};
  }
  bf16x4 r1 = shfl32(h ? pk[0] : pk[1]);
  bf16x4 r2 = shfl32(h ? pk[2] : pk[3]);
  Frag2 out;
  out.f0 = h ? cat44(r1, pk[1]) : cat44(pk[0], r1);
  out.f1 = h ? cat44(r2, pk[3]) : cat44(pk[2], r2);
  return out;
}

__device__ __forceinline__ bf16x8 packf44(float4 a, float4 b) {
  return (bf16x8){(__bf16)a.x, (__bf16)a.y, (__bf16)a.z, (__bf16)a.w,
                  (__bf16)b.x, (__bf16)b.y, (__bf16)b.z, (__bf16)b.w};
}
__device__ __forceinline__ bf16x8 packf2222(float2 a, float2 b, float2 c, float2 d) {
  return (bf16x8){(__bf16)a.x, (__bf16)a.y, (__bf16)b.x, (__bf16)b.y,
                  (__bf16)c.x, (__bf16)c.y, (__bf16)d.x, (__bf16)d.y};
}

__global__ __launch_bounds__(256, 2) void trunk_fused(
    const float* __restrict__ sparse, const float* __restrict__ dec,
    const __bf16* __restrict__ ws, float* __restrict__ out, Biases bp)
{
  __shared__ __align__(16) __bf16 lds[32768];  // 64KB: 2 x 32KB quarter buffers
  __bf16* const buf0 = lds;
  __bf16* const buf1 = lds + QSZ;

  const int tid  = threadIdx.x;
  const int lane = tid & 63;
  const int wid  = tid >> 6;
  const int r32  = lane & 31;     // x-row within wave / W-col within 32-block
  const int h    = lane >> 5;     // k sub-half
  const long grow = (long)blockIdx.x * BM + wid * RPW + r32;

  // issue first stage (MLP0 W0 quarter 0) before the gather, hide latency
  stage<8>(ws, buf0, tid);

  // ---- gather x B-frags: xb[kf] = x[row=r32][k = 16kf + 8h .. +8]; chunk cc = 2kf+h
  // node order [0,3,6,9,12,13,14,15,16,17,18,19,20,21] + parent chain 21..0
  bf16x8 xb[14];
  {
    constexpr int ND[21] = {0,3,6,9,12,13,14,15,16,17,18,19,20,21,19,17,14,9,6,3,0};
    const float* drow = dec + grow * DDEC;
    const float* srow = sparse + grow * DSP;
    #pragma unroll
    for (int kf = 0; kf < 14; ++kf) {
      if (kf <= 9) {
        const int off = (h ? ND[2 * kf + 1] : ND[2 * kf]) * 8;
        const float4* p = (const float4*)(drow + off);
        xb[kf] = packf44(p[0], p[1]);
      } else if (kf == 10) {
        if (h == 0) {
          const float4* p = (const float4*)(drow + ND[20] * 8);
          xb[kf] = packf44(p[0], p[1]);
        } else {
          const float2* q = (const float2*)(srow + 0);
          xb[kf] = packf2222(q[0], q[1], q[2], q[3]);
        }
      } else if (kf <= 12) {
        const float2* q = (const float2*)(srow + (2 * kf + h - 21) * 8);
        xb[kf] = packf2222(q[0], q[1], q[2], q[3]);
      } else {
        if (h == 0) {
          const float2* q = (const float2*)(srow + 40);
          xb[kf] = packf2222(q[0], q[1], q[2], q[3]);
        } else {
          const float2* q = (const float2*)(srow + 48);
          xb[kf] = packf2222(q[0], q[1], q[2], make_float2(1.0f, 0.0f));  // k222 = b0 hook
        }
      }
    }
  }
  __syncthreads();
  int pb = 0;

  for (int m = 0; m < 3; ++m) {
    const __bf16* W0 = ws + m * MLP_WS;
    const __bf16* W1 = W0 + W1_OFF;
    const __bf16* W2 = W0 + W2_OFF;
    const float* b1 = bp.b1[m];
    const float* b2 = bp.b2[m];

    bf16x8 hb1[16], hb2[16];

    // ---- layer 0: 4 quarters, K=224 (14 k-steps), bias folded at k=222
    #pragma unroll
    for (int q = 0; q < 4; ++q) {
      __bf16* cur = pb ? buf1 : buf0;
      __bf16* nxt = pb ? buf0 : buf1;
      stage<8>(q < 3 ? W0 + (q + 1) * QSZ : W1, nxt, tid);
      f32x16 acc0 = {}, acc1 = {};
      gemm2<14>(cur, xb, acc0, acc1, r32, h);
      Frag2 t0 = d2frags<false, true>(acc0, nullptr, h);
      Frag2 t1 = d2frags<false, true>(acc1, nullptr, h);
      hb1[4 * q]     = t0.f0; hb1[4 * q + 1] = t0.f1;
      hb1[4 * q + 2] = t1.f0; hb1[4 * q + 3] = t1.f1;
      __syncthreads();
      pb ^= 1;
    }

    // ---- layer 1: 4 quarters, K=256
    #pragma unroll
    for (int q = 0; q < 4; ++q) {
      __bf16* cur = pb ? buf1 : buf0;
      __bf16* nxt = pb ? buf0 : buf1;
      if (q < 3) stage<8>(W1 + (q + 1) * QSZ, nxt, tid);
      else       stage<4>(W2, nxt, tid);
      f32x16 acc0 = {}, acc1 = {};
      gemm2<16>(cur, hb1, acc0, acc1, r32, h);
      Frag2 t0 = d2frags<true, true>(acc0, b1 + 64 * q, h);
      Frag2 t1 = d2frags<true, true>(acc1, b1 + 64 * q + 32, h);
      hb2[4 * q]     = t0.f0; hb2[4 * q + 1] = t0.f1;
      hb2[4 * q + 2] = t1.f0; hb2[4 * q + 3] = t1.f1;
      __syncthreads();
      pb ^= 1;
    }

    // ---- layer 2: 1 block of 32 padded cols, K=256
    {
      __bf16* cur = pb ? buf1 : buf0;
      __bf16* nxt = pb ? buf0 : buf1;
      if (m < 2) stage<8>(ws + (m + 1) * MLP_WS, nxt, tid);
      f32x16 acc0 = {};
      gemm1<16>(cur, hb2, acc0, r32, h);

      if (m == 2) {
        // lane r32 = its own x-row; quads qi=2t+h -> cols 4qi..+3 (<24 for t<3)
        #pragma unroll
        for (int t = 0; t < 3; ++t) {
          const int c0 = 8 * t + 4 * h;
          float4 bv = *(const float4*)(b2 + c0);
          float4 o;
          o.x = acc0[4 * t]     + bv.x;
          o.y = acc0[4 * t + 1] + bv.y;
          o.z = acc0[4 * t + 2] + bv.z;
          o.w = acc0[4 * t + 3] + bv.w;
          *(float4*)(out + grow * 24 + c0) = o;
        }
      } else {
        bf16x4 pk[3];
        #pragma unroll
        for (int t = 0; t < 3; ++t) {
          const int c0 = 8 * t + 4 * h;
          float4 bv = *(const float4*)(b2 + c0);
          pk[t] = (bf16x4){(__bf16)(acc0[4 * t] + bv.x),     (__bf16)(acc0[4 * t + 1] + bv.y),
                           (__bf16)(acc0[4 * t + 2] + bv.z), (__bf16)(acc0[4 * t + 3] + bv.w)};
        }
        if (m == 0) {
          // res1 = joint 9 (cols 0-7) -> chunks 3 (xb[1],h1) and 17 (xb[8],h1)
          bf16x4 r = shfl32(pk[0]);
          if (h) { bf16x8 f = cat44(r, pk[0]); xb[1] = f; xb[8] = f; }
        } else {
          // res2: joint6 (0-7)->chunks 2,18 (h0); joint9 (8-15)->3,17 (h1); joint12 (16-23)->4 (h0)
          bf16x4 r1 = shfl32(h ? pk[0] : pk[1]);
          bf16x4 r2 = shfl32(pk[2]);
          if (h) {
            bf16x8 fJ9 = cat44(r1, pk[1]);  xb[1] = fJ9;  xb[8] = fJ9;
          } else {
            bf16x8 fJ6  = cat44(pk[0], r1); xb[1] = fJ6;  xb[9] = fJ6;
            bf16x8 fJ12 = cat44(pk[2], r2); xb[2] = fJ12;
          }
        }
      }
      __syncthreads();
      pb ^= 1;
    }
  }
}

extern "C" void kernel_launch(void* const* d_in, const int* in_sizes, int n_in,
                              void* d_out, int out_size, void* d_ws, size_t ws_size,
                              hipStream_t stream)
{
  const float* sparse = (const float*)d_in[0];
  const float* dec    = (const float*)d_in[1];
  Biases bp;
  const float* w0[3]; const float* w1[3]; const float* w2[3]; const float* b0[3];
  for (int m = 0; m < 3; ++m) {
    w0[m]    = (const float*)d_in[2 + m * 6 + 0];
    b0[m]    = (const float*)d_in[2 + m * 6 + 1];
    w1[m]    = (const float*)d_in[2 + m * 6 + 2];
    bp.b1[m] = (const float*)d_in[2 + m * 6 + 3];
    w2[m]    = (const float*)d_in[2 + m * 6 + 4];
    bp.b2[m] = (const float*)d_in[2 + m * 6 + 5];
  }
  __bf16* ws = (__bf16*)d_ws;
  const int nrows = in_sizes[0] / DSP;   // 131072 = 1024 * 128

  const int prep_total = 3 * MLP_WS;
  prep_weights<<<(prep_total + 255) / 256, 256, 0, stream>>>(
      w0[0], w1[0], w2[0], w0[1], w1[1], w2[1], w0[2], w1[2], w2[2],
      b0[0], b0[1], b0[2], ws);

  const int nblocks = nrows / BM;
  trunk_fused<<<nblocks, 256, 0, stream>>>(sparse, dec, ws, (float*)d_out, bp);
}

// Round 7
// 139.211 us; speedup vs baseline: 5.1429x; 1.3096x over previous
//
#include <hip/hip_runtime.h>

typedef __bf16 bf16x8 __attribute__((ext_vector_type(8)));
typedef __bf16 bf16x4 __attribute__((ext_vector_type(4)));
typedef float  f32x16 __attribute__((ext_vector_type(16)));

#define DDEC  176
#define DSP   54
#define HID   256
#define RPW   32             // rows per wave (32x32 MFMA N-dim)
#define WPB   4              // waves per block
#define BM    (RPW * WPB)    // 128 rows per block
#define QSZ   16384          // elems per 64-col weight quarter
#define W1_OFF 65536
#define W2_OFF 131072
#define MLP_WS 139264

struct Biases { const float* b1[3]; const float* b2[3]; };

// ---- prep: pad/transpose weights to bf16 [col][256 k] per layer
// W0p[256][256] (k<222 = w0[k][n], k==222 = b0[n], else 0), W1p[256][256], W2p[32][256]
__global__ __launch_bounds__(256) void prep_weights(
    const float* __restrict__ w0a, const float* __restrict__ w1a, const float* __restrict__ w2a,
    const float* __restrict__ w0b, const float* __restrict__ w1b, const float* __restrict__ w2b,
    const float* __restrict__ w0c, const float* __restrict__ w1c, const float* __restrict__ w2c,
    const float* __restrict__ b0a, const float* __restrict__ b0b, const float* __restrict__ b0c,
    __bf16* __restrict__ ws)
{
  int idx = blockIdx.x * 256 + threadIdx.x;
  if (idx >= 3 * MLP_WS) return;
  int m = idx / MLP_WS;
  int r = idx - m * MLP_WS;
  const float* w0 = (m == 0) ? w0a : (m == 1) ? w0b : w0c;
  const float* w1 = (m == 0) ? w1a : (m == 1) ? w1b : w1c;
  const float* w2 = (m == 0) ? w2a : (m == 1) ? w2b : w2c;
  const float* b0 = (m == 0) ? b0a : (m == 1) ? b0b : b0c;
  float v;
  if (r < W1_OFF) {
    int n = r >> 8, k = r & 255;
    v = (k < 222) ? w0[k * HID + n] : (k == 222 ? b0[n] : 0.0f);
  } else if (r < W2_OFF) {
    int rr = r - W1_OFF;
    int n = rr >> 8, k = rr & 255;
    v = w1[k * HID + n];
  } else {
    int rr = r - W2_OFF;
    int n = rr >> 8, k = rr & 255;
    int od = (m == 0) ? 8 : 24;
    v = (n < od) ? w2[k * od + n] : 0.0f;
  }
  ws[idx] = (__bf16)v;
}

__device__ __forceinline__ float lrelu(float v) { return v > 0.f ? v : 0.01f * v; }

__device__ __forceinline__ void gload16(const void* g, void* l) {
  __builtin_amdgcn_global_load_lds(
      (const __attribute__((address_space(1))) void*)g,
      (__attribute__((address_space(3))) void*)l, 16, 0, 0);
}

// stage ROUNDS*4KB of [col][256k] weights; source pre-swizzled so LDS byte a holds
// W[col = a>>9][k_byte = (a&511) ^ ((col&31)<<4)]
template<int ROUNDS>
__device__ __forceinline__ void stage(const __bf16* __restrict__ wsrc, __bf16* buf, int tid) {
  #pragma unroll
  for (int r = 0; r < ROUNDS; ++r) {
    const int a  = (r * 256 + tid) * 16;
    const int lc = a >> 9;
    const int un = (a & 511) ^ ((lc & 31) << 4);
    gload16(wsrc + lc * 256 + (un >> 1), (char*)buf + r * 4096 + (tid >> 6) * 1024);
  }
}

// 64-col quarter: acc{0,1} += W[32b+r32][k] x B[k]  (swizzled ds_read_b128 A-frags)
template<int NKK>
__device__ __forceinline__ void gemm2(const __bf16* buf, const bf16x8* bfr,
                                      f32x16& acc0, f32x16& acc1, int r32, int h) {
  const int sw = r32 << 4;
  #pragma unroll
  for (int kk = 0; kk < NKK; ++kk) {
    const int inner = ((kk << 5) + (h << 4)) ^ sw;
    bf16x8 a0 = *(const bf16x8*)((const char*)buf + (r32 << 9) + inner);
    bf16x8 a1 = *(const bf16x8*)((const char*)buf + ((32 + r32) << 9) + inner);
    acc0 = __builtin_amdgcn_mfma_f32_32x32x16_bf16(a0, bfr[kk], acc0, 0, 0, 0);
    acc1 = __builtin_amdgcn_mfma_f32_32x32x16_bf16(a1, bfr[kk], acc1, 0, 0, 0);
  }
}

__device__ __forceinline__ bf16x4 shfl32(bf16x4 x) {
  union { bf16x4 v; unsigned long long u; } t;
  t.v = x;
  t.u = __shfl_xor(t.u, 32, 64);
  return t.v;
}
__device__ __forceinline__ bf16x8 cat44(bf16x4 lo, bf16x4 hi) {
  return (bf16x8){lo[0], lo[1], lo[2], lo[3], hi[0], hi[1], hi[2], hi[3]};
}

struct Frag2 { bf16x8 f0, f1; };

// One 32-col D block -> 2 next-layer B-frags (k = 32nb..+16, 32nb+16..+32).
// D layout (verified): n = lane&31, m = (reg&3) + 8*(reg>>2) + 4*h. Lane-half h owns
// quads {2t+h}; one shfl_xor(32) per 2 quads completes each frag.
template<bool BIAS, bool LR>
__device__ __forceinline__ Frag2 d2frags(const f32x16 acc, const float* bias, int h) {
  bf16x4 pk[4];
  #pragma unroll
  for (int t = 0; t < 4; ++t) {
    float bx = 0.f, by = 0.f, bz = 0.f, bw = 0.f;
    if (BIAS) {
      float4 bv = *(const float4*)(bias + 8 * t + 4 * h);
      bx = bv.x; by = bv.y; bz = bv.z; bw = bv.w;
    }
    float v0 = acc[4 * t] + bx, v1 = acc[4 * t + 1] + by;
    float v2 = acc[4 * t + 2] + bz, v3 = acc[4 * t + 3] + bw;
    if (LR) { v0 = lrelu(v0); v1 = lrelu(v1); v2 = lrelu(v2); v3 = lrelu(v3); }
    pk[t] = (bf16x4){(__bf16)v0, (__bf16)v1, (__bf16)v2, (__bf16)v3};
  }
  bf16x4 r1 = shfl32(h ? pk[0] : pk[1]);
  bf16x4 r2 = shfl32(h ? pk[2] : pk[3]);
  Frag2 out;
  out.f0 = h ? cat44(r1, pk[1]) : cat44(pk[0], r1);
  out.f1 = h ? cat44(r2, pk[3]) : cat44(pk[2], r2);
  return out;
}

__device__ __forceinline__ bf16x8 packf44(float4 a, float4 b) {
  return (bf16x8){(__bf16)a.x, (__bf16)a.y, (__bf16)a.z, (__bf16)a.w,
                  (__bf16)b.x, (__bf16)b.y, (__bf16)b.z, (__bf16)b.w};
}
__device__ __forceinline__ bf16x8 packf2222(float2 a, float2 b, float2 c, float2 d) {
  return (bf16x8){(__bf16)a.x, (__bf16)a.y, (__bf16)b.x, (__bf16)b.y,
                  (__bf16)c.x, (__bf16)c.y, (__bf16)d.x, (__bf16)d.y};
}

__global__ __launch_bounds__(256, 2) void trunk_fused(
    const float* __restrict__ sparse, const float* __restrict__ dec,
    const __bf16* __restrict__ ws, float* __restrict__ out, Biases bp)
{
  __shared__ __align__(16) __bf16 lds[32768];  // 64KB: 2 x 32KB quarter buffers
  __bf16* const buf0 = lds;
  __bf16* const buf1 = lds + QSZ;

  const int tid  = threadIdx.x;
  const int lane = tid & 63;
  const int wid  = tid >> 6;
  const int r32  = lane & 31;     // x-row within wave / W-col within 32-block
  const int h    = lane >> 5;     // k sub-half
  const long grow = (long)blockIdx.x * BM + wid * RPW + r32;

  // issue first stage (MLP0 W0 quarter 0) before the gather, hide latency
  stage<8>(ws, buf0, tid);

  // ---- gather x B-frags: xb[kf] = x[row=r32][k = 16kf + 8h .. +8]; chunk cc = 2kf+h
  // node order [0,3,6,9,12,13,14,15,16,17,18,19,20,21] + parent chain 21..0
  bf16x8 xb[14];
  {
    constexpr int ND[21] = {0,3,6,9,12,13,14,15,16,17,18,19,20,21,19,17,14,9,6,3,0};
    const float* drow = dec + grow * DDEC;
    const float* srow = sparse + grow * DSP;
    #pragma unroll
    for (int kf = 0; kf < 14; ++kf) {
      if (kf <= 9) {
        const int off = (h ? ND[2 * kf + 1] : ND[2 * kf]) * 8;
        const float4* p = (const float4*)(drow + off);
        xb[kf] = packf44(p[0], p[1]);
      } else if (kf == 10) {
        if (h == 0) {
          const float4* p = (const float4*)(drow + ND[20] * 8);
          xb[kf] = packf44(p[0], p[1]);
        } else {
          const float2* q = (const float2*)(srow + 0);
          xb[kf] = packf2222(q[0], q[1], q[2], q[3]);
        }
      } else if (kf <= 12) {
        const float2* q = (const float2*)(srow + (2 * kf + h - 21) * 8);
        xb[kf] = packf2222(q[0], q[1], q[2], q[3]);
      } else {
        if (h == 0) {
          const float2* q = (const float2*)(srow + 40);
          xb[kf] = packf2222(q[0], q[1], q[2], q[3]);
        } else {
          const float2* q = (const float2*)(srow + 48);
          xb[kf] = packf2222(q[0], q[1], q[2], make_float2(1.0f, 0.0f));  // k222 = b0 hook
        }
      }
    }
  }
  __syncthreads();
  int pb = 0;

  for (int m = 0; m < 3; ++m) {
    const __bf16* W0 = ws + m * MLP_WS;
    const __bf16* W1 = W0 + W1_OFF;
    const __bf16* W2 = W0 + W2_OFF;
    const float* b1 = bp.b1[m];
    const float* b2 = bp.b2[m];

    bf16x8 hb1[16];
    f32x16 a2 = {};   // layer-2 accumulator, filled across the 4 layer-1 quarters

    // ---- layer 0: 4 quarters, K=224 (14 k-steps), bias folded at k=222
    #pragma unroll
    for (int q = 0; q < 4; ++q) {
      __bf16* cur = pb ? buf1 : buf0;
      __bf16* nxt = pb ? buf0 : buf1;
      stage<8>(q < 3 ? W0 + (q + 1) * QSZ : W1, nxt, tid);
      f32x16 acc0 = {}, acc1 = {};
      gemm2<14>(cur, xb, acc0, acc1, r32, h);
      Frag2 t0 = d2frags<false, true>(acc0, nullptr, h);
      Frag2 t1 = d2frags<false, true>(acc1, nullptr, h);
      hb1[4 * q]     = t0.f0; hb1[4 * q + 1] = t0.f1;
      hb1[4 * q + 2] = t1.f0; hb1[4 * q + 3] = t1.f1;
      __syncthreads();
      pb ^= 1;
    }

    // ---- layer 1 (4 quarters, K=256) with layer 2 folded in per quarter.
    // Layer-2 A-frags (W2, 16KB, L2-hot) are read straight from global, issued
    // before gemm2 so the latency hides under the 32 MFMAs.
    #pragma unroll
    for (int q = 0; q < 4; ++q) {
      __bf16* cur = pb ? buf1 : buf0;
      __bf16* nxt = pb ? buf0 : buf1;
      const __bf16* w2f = W2 + r32 * 256 + h * 8 + 64 * q;
      bf16x8 wa0 = *(const bf16x8*)(w2f + 0);
      bf16x8 wa1 = *(const bf16x8*)(w2f + 16);
      bf16x8 wa2 = *(const bf16x8*)(w2f + 32);
      bf16x8 wa3 = *(const bf16x8*)(w2f + 48);
      if (q < 3)      stage<8>(W1 + (q + 1) * QSZ, nxt, tid);
      else if (m < 2) stage<8>(ws + (m + 1) * MLP_WS, nxt, tid);
      f32x16 acc0 = {}, acc1 = {};
      gemm2<16>(cur, hb1, acc0, acc1, r32, h);
      Frag2 t0 = d2frags<true, true>(acc0, b1 + 64 * q, h);
      Frag2 t1 = d2frags<true, true>(acc1, b1 + 64 * q + 32, h);
      a2 = __builtin_amdgcn_mfma_f32_32x32x16_bf16(wa0, t0.f0, a2, 0, 0, 0);
      a2 = __builtin_amdgcn_mfma_f32_32x32x16_bf16(wa1, t0.f1, a2, 0, 0, 0);
      a2 = __builtin_amdgcn_mfma_f32_32x32x16_bf16(wa2, t1.f0, a2, 0, 0, 0);
      a2 = __builtin_amdgcn_mfma_f32_32x32x16_bf16(wa3, t1.f1, a2, 0, 0, 0);
      __syncthreads();
      pb ^= 1;
    }

    // ---- epilogue: a2 = out^T frag (lane r32 = its own x-row; quads 2t+h -> cols 8t+4h..+3)
    if (m == 2) {
      #pragma unroll
      for (int t = 0; t < 3; ++t) {
        const int c0 = 8 * t + 4 * h;
        float4 bv = *(const float4*)(b2 + c0);
        float4 o;
        o.x = a2[4 * t]     + bv.x;
        o.y = a2[4 * t + 1] + bv.y;
        o.z = a2[4 * t + 2] + bv.z;
        o.w = a2[4 * t + 3] + bv.w;
        *(float4*)(out + grow * 24 + c0) = o;
      }
    } else {
      bf16x4 pk[3];
      #pragma unroll
      for (int t = 0; t < 3; ++t) {
        const int c0 = 8 * t + 4 * h;
        float4 bv = *(const float4*)(b2 + c0);
        pk[t] = (bf16x4){(__bf16)(a2[4 * t] + bv.x),     (__bf16)(a2[4 * t + 1] + bv.y),
                         (__bf16)(a2[4 * t + 2] + bv.z), (__bf16)(a2[4 * t + 3] + bv.w)};
      }
      if (m == 0) {
        // res1 = joint 9 (cols 0-7) -> chunks 3 (xb[1],h1) and 17 (xb[8],h1)
        bf16x4 r = shfl32(pk[0]);
        if (h) { bf16x8 f = cat44(r, pk[0]); xb[1] = f; xb[8] = f; }
      } else {
        // res2: joint6 (0-7)->chunks 2,18 (h0); joint9 (8-15)->3,17 (h1); joint12 (16-23)->4 (h0)
        bf16x4 r1 = shfl32(h ? pk[0] : pk[1]);
        bf16x4 r2 = shfl32(pk[2]);
        if (h) {
          bf16x8 fJ9 = cat44(r1, pk[1]);  xb[1] = fJ9;  xb[8] = fJ9;
        } else {
          bf16x8 fJ6  = cat44(pk[0], r1); xb[1] = fJ6;  xb[9] = fJ6;
          bf16x8 fJ12 = cat44(pk[2], r2); xb[2] = fJ12;
        }
      }
    }
  }
}

extern "C" void kernel_launch(void* const* d_in, const int* in_sizes, int n_in,
                              void* d_out, int out_size, void* d_ws, size_t ws_size,
                              hipStream_t stream)
{
  const float* sparse = (const float*)d_in[0];
  const float* dec    = (const float*)d_in[1];
  Biases bp;
  const float* w0[3]; const float* w1[3]; const float* w2[3]; const float* b0[3];
  for (int m = 0; m < 3; ++m) {
    w0[m]    = (const float*)d_in[2 + m * 6 + 0];
    b0[m]    = (const float*)d_in[2 + m * 6 + 1];
    w1[m]    = (const float*)d_in[2 + m * 6 + 2];
    bp.b1[m] = (const float*)d_in[2 + m * 6 + 3];
    w2[m]    = (const float*)d_in[2 + m * 6 + 4];
    bp.b2[m] = (const float*)d_in[2 + m * 6 + 5];
  }
  __bf16* ws = (__bf16*)d_ws;
  const int nrows = in_sizes[0] / DSP;   // 131072 = 1024 * 128

  const int prep_total = 3 * MLP_WS;
  prep_weights<<<(prep_total + 255) / 256, 256, 0, stream>>>(
      w0[0], w1[0], w2[0], w0[1], w1[1], w2[1], w0[2], w1[2], w2[2],
      b0[0], b0[1], b0[2], ws);

  const int nblocks = nrows / BM;
  trunk_fused<<<nblocks, 256, 0, stream>>>(sparse, dec, ws, (float*)d_out, bp);
}